// Round 9
// baseline (189.563 us; speedup 1.0000x reference)
//
#include <hip/hip_runtime.h>
#include <hip/hip_bf16.h>

// Problem: B=8, T=1024, C=768, H=12, HD=64. M = 8192. fp32 in/out.
// R22: attn restructured for intra-wave ILP (T15-style 2-chain pipeline).
// The paired q-tiles (B,A) previously ran strictly serial per iteration,
// each re-reading identical K/V frags, each chain exposing its own
// ds-latency + softmax + Ps-LDS-round-trip serially (~700cyc x 17 tiles,
// only 4 waves/block of cover). Now: QK-B, QK-A, SM-B, SM-A, PV-B, PV-A
// with TWO Ps buffers (one per tile) -> the two independent chains hide
// each other's lgkm/VALU latency. Diag iterations peeled (A-diag at
// kt==qtA, B-diag at kt==qtB) so non-diag tiles carry no mask work.
// Arithmetic order per value identical -> bit-identical output.
// LDS 25.3->51.2KB (3 blocks/CU). qkv (R15) + proj (R17) + precast (R17)
// unchanged.

#define TDIM 1024
#define CDIM 768
#define NDIM 2304

typedef __attribute__((ext_vector_type(8))) short bf16x8;
typedef __attribute__((ext_vector_type(8))) unsigned short u16x8;
typedef __attribute__((ext_vector_type(4))) float f32x4;

__device__ __forceinline__ unsigned short f2bf(float f) {
    unsigned int u;
    __builtin_memcpy(&u, &f, 4);
    u += 0x7FFFu + ((u >> 16) & 1u);  // RNE
    return (unsigned short)(u >> 16);
}

__device__ __forceinline__ void async_copy16(void* lds, const void* g) {
    __builtin_amdgcn_global_load_lds(
        (const __attribute__((address_space(1))) void*)g,
        (__attribute__((address_space(3))) void*)lds, 16, 0, 0);
}

// ---------------------------------------------------------------------------
// Precast: one fat kernel. Blocks [0,6144): cast x -> xb (bf16).
// [6144,7872): transpose-cast W_attn -> Wta. [7872,8448): W_proj -> Wtp.
// ---------------------------------------------------------------------------
__global__ __launch_bounds__(256) void precast(
    const float* __restrict__ x, unsigned short* __restrict__ xb,
    const float* __restrict__ Wa, unsigned short* __restrict__ Wta,
    const float* __restrict__ Wp, unsigned short* __restrict__ Wtp)
{
    __shared__ float tile[32][33];
    int bid = blockIdx.x;
    const int tid = threadIdx.x;

    if (bid < 6144) {
        const size_t i = ((size_t)bid * 256 + tid) * 4;
        float4 v = *(const float4*)&x[i];
        ushort4 s;
        s.x = f2bf(v.x); s.y = f2bf(v.y); s.z = f2bf(v.z); s.w = f2bf(v.w);
        *(ushort4*)&xb[i] = s;
        return;
    }
    bid -= 6144;
    const float* W;
    unsigned short* Wt;
    int N, bx, by;
    if (bid < 1728) {
        W = Wa; Wt = Wta; N = NDIM; bx = bid % 72; by = bid / 72;
    } else {
        bid -= 1728;
        W = Wp; Wt = Wtp; N = CDIM; bx = bid % 24; by = bid / 24;
    }
    const int n0 = bx * 32;
    const int k0 = by * 32;
    const int tx = tid & 31;
    const int ty = tid >> 5;
#pragma unroll
    for (int i = 0; i < 4; ++i)
        tile[ty + i * 8][tx] = W[(size_t)(k0 + ty + i * 8) * N + n0 + tx];
    __syncthreads();
#pragma unroll
    for (int i = 0; i < 4; ++i)
        Wt[(size_t)(n0 + ty + i * 8) * CDIM + k0 + tx] = f2bf(tile[tx][ty + i * 8]);
}

// ---------------------------------------------------------------------------
// Kernel 1: qkv GEMM — 128(M) x 256(N) tile, BK=32, 8 waves (2M x 4N),
// 3-buffer LDS, depth-2 prefetch, vmcnt(3) per tile, 2 blocks/CU. (R15)
// ---------------------------------------------------------------------------
__global__ __launch_bounds__(512, 4) void qkv_mfma(
    const unsigned short* __restrict__ xb, const unsigned short* __restrict__ Wt,
    const float* __restrict__ bias,
    unsigned short* __restrict__ Q, unsigned short* __restrict__ Kd,
    unsigned short* __restrict__ Vt)
{
    // XCD-aware swizzle: 576 blocks, 576 % 8 == 0 -> bijective.
    const int wg = ((int)blockIdx.x & 7) * 72 + ((int)blockIdx.x >> 3);
    const int bx = wg % 9;
    const int by = wg / 9;
    const int n0 = bx * 256;
    const int m0 = by * 128;
    const int tid = threadIdx.x;
    const int lane = tid & 63;
    const int w = tid >> 6;
    const int wm = w >> 2;   // 0..1
    const int wn = w & 3;    // 0..3
    const int lm = lane & 15;
    const int lq = lane >> 4;

    __shared__ __align__(16) unsigned short lds[36864];  // 72 KiB (3 x 24KB)

    float bb[4];
#pragma unroll
    for (int ni = 0; ni < 4; ++ni) bb[ni] = bias[n0 + wn * 64 + ni * 16 + lm];

    f32x4 acc[4][4] = {};

    // ds_read swizzled chunk: eo = lq ^ ((lm>>1)&3).
    const int eo = lq ^ ((lm >> 1) & 3);
    int aoffc[4], boffc[4];
#pragma unroll
    for (int mi = 0; mi < 4; ++mi)
        aoffc[mi] = (wm * 64 + mi * 16 + lm) * 32 + eo * 8;
#pragma unroll
    for (int ni = 0; ni < 4; ++ni)
        boffc[ni] = 4096 + (wn * 64 + ni * 16 + lm) * 32 + eo * 8;

    const int rowA = tid >> 2;
    const int ccA = (tid & 3) ^ ((rowA >> 1) & 3);
    const int srcA = rowA * CDIM + ccA * 8;          // + m0*CDIM + kt*32
    int srcB[2];
#pragma unroll
    for (int j = 0; j < 2; ++j) {
        const int lin = j * 512 + tid;
        const int rowB = lin >> 2;
        const int ccB = (lin & 3) ^ ((rowB >> 1) & 3);
        srcB[j] = rowB * CDIM + ccB * 8;             // + n0*CDIM + kt*32
    }
    const unsigned short* xbb = xb + (size_t)m0 * CDIM;
    const unsigned short* Wtb = Wt + (size_t)n0 * CDIM;

#define STAGE(p, kt)                                                            \
    do {                                                                        \
        async_copy16(&lds[(p) * 12288 + w * 512], &xbb[srcA + (kt) * 32]);      \
        _Pragma("unroll")                                                       \
        for (int j = 0; j < 2; ++j)                                             \
            async_copy16(&lds[(p) * 12288 + 4096 + j * 4096 + w * 512],         \
                         &Wtb[srcB[j] + (kt) * 32]);                            \
    } while (0)

#define TILE(p, ktn)                                                            \
    do {                                                                        \
        STAGE((p + 2) % 3, ktn);                                                \
        bf16x8 a[4], b[4];                                                      \
        _Pragma("unroll")                                                       \
        for (int mi = 0; mi < 4; ++mi)                                          \
            a[mi] = *(const bf16x8*)&lds[(p) * 12288 + aoffc[mi]];              \
        _Pragma("unroll")                                                       \
        for (int ni = 0; ni < 4; ++ni)                                          \
            b[ni] = *(const bf16x8*)&lds[(p) * 12288 + boffc[ni]];              \
        __builtin_amdgcn_s_setprio(1);                                          \
        _Pragma("unroll")                                                       \
        for (int mi = 0; mi < 4; ++mi)                                          \
            _Pragma("unroll")                                                   \
            for (int ni = 0; ni < 4; ++ni)                                      \
                acc[mi][ni] = __builtin_amdgcn_mfma_f32_16x16x32_bf16(          \
                    a[mi], b[ni], acc[mi][ni], 0, 0, 0);                        \
        __builtin_amdgcn_s_setprio(0);                                          \
        asm volatile("s_waitcnt vmcnt(3)" ::: "memory");                        \
        __builtin_amdgcn_s_barrier();                                           \
    } while (0)

    STAGE(0, 0);
    STAGE(1, 1);
    asm volatile("s_waitcnt vmcnt(3)" ::: "memory");
    __builtin_amdgcn_s_barrier();

#pragma unroll 1
    for (int it = 0; it < 8; ++it) {
        const int k2 = (3 * it + 2 < 24) ? 3 * it + 2 : 23;
        const int k3 = (3 * it + 3 < 24) ? 3 * it + 3 : 23;  // clamp: dead
        const int k4 = (3 * it + 4 < 24) ? 3 * it + 4 : 23;  // restage benign
        TILE(0, k2);
        TILE(1, k3);
        TILE(2, k4);
    }

#undef STAGE
#undef TILE

    // Drain all outstanding DMA before reusing LDS as epilogue scratch.
    asm volatile("s_waitcnt vmcnt(0)" ::: "memory");
    __builtin_amdgcn_s_barrier();

    // Epilogue. Wave's 64-col group: ga = bx*4 + wn; which = ga%3; h = ga/3.
    const int ga = bx * 4 + wn;
    const int which = ga % 3;
    const int h = ga / 3;

    if (which == 2) {
        // V transposed [B,H,D,T]: direct t-contiguous ushort4 stores.
#pragma unroll
        for (int ni = 0; ni < 4; ++ni) {
            const int d = ni * 16 + lm;
#pragma unroll
            for (int mi = 0; mi < 4; ++mi) {
                const int gm0 = m0 + wm * 64 + mi * 16 + lq * 4;
                const int bidx = gm0 >> 10;
                const int t0 = gm0 & 1023;
                ushort4 sv;
                sv.x = f2bf(acc[mi][ni][0] + bb[ni]);
                sv.y = f2bf(acc[mi][ni][1] + bb[ni]);
                sv.z = f2bf(acc[mi][ni][2] + bb[ni]);
                sv.w = f2bf(acc[mi][ni][3] + bb[ni]);
                *(ushort4*)&Vt[(((size_t)bidx * 12 + h) * 64 + d) * TDIM + t0] = sv;
            }
        }
    } else {
        // Q/K [B,H,T,64]: per-wave LDS transpose -> 16B row stores.
        unsigned short* dst = (which == 0) ? Q : Kd;
        unsigned short* Es = &lds[w * 1152];  // 16 x 72 per wave
        const int erow = lane >> 2;   // 0..15
        const int ecol = lane & 3;    // 0..3 -> 16-short chunks
#pragma unroll
        for (int mi = 0; mi < 4; ++mi) {
#pragma unroll
            for (int r = 0; r < 4; ++r)
#pragma unroll
                for (int ni = 0; ni < 4; ++ni)
                    Es[(lq * 4 + r) * 72 + ni * 16 + lm] = f2bf(acc[mi][ni][r] + bb[ni]);
            // same-wave LDS write->read (in-order per wave; validated since R7)
            const int t = m0 + wm * 64 + mi * 16 + erow;
            const int bidx = t >> 10;
            const int tt = t & 1023;
            unsigned short* drow = &dst[(((size_t)bidx * 12 + h) * TDIM + tt) * 64];
            u16x8 v0 = *(const u16x8*)&Es[erow * 72 + ecol * 16];
            u16x8 v1 = *(const u16x8*)&Es[erow * 72 + ecol * 16 + 8];
            *(u16x8*)&drow[ecol * 16] = v0;
            *(u16x8*)&drow[ecol * 16 + 8] = v1;
        }
    }
}

// ---------------------------------------------------------------------------
// Kernel 2: MFMA causal flash attention v6 — R16 staging + math, restructured
// as a 2-chain pipeline: QK-B, QK-A, SM-B, SM-A, PV-B, PV-A with per-tile Ps
// buffers; diag iterations peeled. Bit-identical arithmetic to v5.
// ---------------------------------------------------------------------------
#define QK_PART(sf, aq, ksb) do {                                               \
    _Pragma("unroll")                                                           \
    for (int nt = 0; nt < 4; ++nt) {                                            \
        f32x4 s = {};                                                           \
        _Pragma("unroll")                                                       \
        for (int kc = 0; kc < 2; ++kc) {                                        \
            bf16x8 bfrag = *(const bf16x8*)&(ksb)[(nt * 16 + lm) * 64 + cofs[kc]]; \
            s = __builtin_amdgcn_mfma_f32_16x16x32_bf16(aq[kc], bfrag, s, 0, 0, 0); \
        }                                                                       \
        sf[nt] = s;                                                             \
    }                                                                           \
} while (0)

#define SM_PART(sf, l_p, ps, DIAG, q0t) do {                                    \
    float pf[4][4];                                                             \
    _Pragma("unroll")                                                           \
    for (int nt = 0; nt < 4; ++nt) {                                            \
        _Pragma("unroll")                                                       \
        for (int r = 0; r < 4; ++r) {                                           \
            float p = __builtin_amdgcn_exp2f(sf[nt][r] * SC);                   \
            if (DIAG) {                                                         \
                const int keyg = kbase + nt * 16 + lm;                          \
                const int qg = (q0t) + w * 16 + lq * 4 + r;                     \
                if (keyg > qg) p = 0.f;                                         \
            }                                                                   \
            pf[nt][r] = p;                                                      \
        }                                                                       \
    }                                                                           \
    _Pragma("unroll")                                                           \
    for (int r = 0; r < 4; ++r) {                                               \
        l_p[r] += pf[0][r] + pf[1][r] + pf[2][r] + pf[3][r];                    \
        _Pragma("unroll")                                                       \
        for (int nt = 0; nt < 4; ++nt)                                          \
            (ps)[(lq * 4 + r) * 72 + nt * 16 + lm] = f2bf(pf[nt][r]);           \
    }                                                                           \
} while (0)

#define PV_PART(o, ps, vsb) do {                                                \
    bf16x8 ap[2];                                                               \
    _Pragma("unroll")                                                           \
    for (int kc = 0; kc < 2; ++kc)                                              \
        ap[kc] = *(const bf16x8*)&(ps)[lm * 72 + kc * 32 + lq * 8];             \
    _Pragma("unroll")                                                           \
    for (int nt = 0; nt < 4; ++nt) {                                            \
        _Pragma("unroll")                                                       \
        for (int kc = 0; kc < 2; ++kc) {                                        \
            bf16x8 bv = *(const bf16x8*)&(vsb)[(nt * 16 + lm) * 64 + cofs[kc]]; \
            o[nt] = __builtin_amdgcn_mfma_f32_16x16x32_bf16(ap[kc], bv, o[nt], 0, 0, 0); \
        }                                                                       \
    }                                                                           \
} while (0)

#define ATTN_EPI(q0t, l_p, o) do {                                              \
    _Pragma("unroll")                                                           \
    for (int r = 0; r < 4; ++r) {                                               \
        float l = l_p[r];                                                       \
        _Pragma("unroll")                                                       \
        for (int off = 1; off < 16; off <<= 1) l += __shfl_xor(l, off);         \
        const float inv = 1.0f / l;                                             \
        const int qg = (q0t) + w * 16 + lq * 4 + r;                             \
        _Pragma("unroll")                                                       \
        for (int nt = 0; nt < 4; ++nt)                                          \
            Yb[(size_t)qg * 64 + nt * 16 + lm] = f2bf(o[nt][r] * inv);          \
    }                                                                           \
} while (0)

__global__ __launch_bounds__(256) void attn_mfma(
    const unsigned short* __restrict__ Q, const unsigned short* __restrict__ K,
    const unsigned short* __restrict__ Vt, unsigned short* __restrict__ Y)
{
    const int pi = blockIdx.x;        // 0..7 -> 64-query tiles (pi, 15-pi)
    const int bh = blockIdx.y;        // 0..95
    const int qtA = pi, qtB = 15 - pi;
    const int q0A = qtA * 64, q0B = qtB * 64;
    const int tid = threadIdx.x;
    const int lane = tid & 63;
    const int w = tid >> 6;
    const int lm = lane & 15;
    const int lq = lane >> 4;

    __shared__ __align__(16) unsigned short Ks2[2][4096];   // [buf][64*64] linear
    __shared__ __align__(16) unsigned short Vts2[2][4096];  // [buf][d*64+key]
    __shared__ __align__(16) unsigned short Ps[2][4][16 * 72];  // [tile][wave]

    const unsigned short* Qb = Q + (size_t)bh * TDIM * 64;
    const unsigned short* Kb = K + (size_t)bh * TDIM * 64;
    const unsigned short* Vtb = Vt + (size_t)bh * 64 * TDIM;
    unsigned short* Yb = Y + (size_t)bh * TDIM * 64;

    bf16x8 aqA[2], aqB[2];
#pragma unroll
    for (int kc = 0; kc < 2; ++kc) {
        aqA[kc] = *(const bf16x8*)&Qb[(size_t)(q0A + w * 16 + lm) * 64 + kc * 32 + lq * 8];
        aqB[kc] = *(const bf16x8*)&Qb[(size_t)(q0B + w * 16 + lm) * 64 + kc * 32 + lq * 8];
    }

    int dstO[2], srcK[2], srcV[2];
#pragma unroll
    for (int it = 0; it < 2; ++it) {
        const int idx = it * 256 + tid;
        const int row = idx >> 3;
        const int cc = (idx & 7) ^ (row & 7);
        dstO[it] = idx * 8;                 // shorts
        srcK[it] = row * 64 + cc * 8;       // + kbase*64
        srcV[it] = row * TDIM + cc * 8;     // + kbase
    }
    int cofs[2];
#pragma unroll
    for (int kc = 0; kc < 2; ++kc)
        cofs[kc] = (((kc * 4 + lq) ^ (lm & 7)) * 8);

#define AST(bf, kb)                                                             \
    do {                                                                        \
        _Pragma("unroll")                                                       \
        for (int it = 0; it < 2; ++it) {                                        \
            async_copy16(&Ks2[bf][dstO[it]], &Kb[(size_t)(kb) * 64 + srcK[it]]); \
            async_copy16(&Vts2[bf][dstO[it]], &Vtb[(size_t)(kb) + srcV[it]]);   \
        }                                                                       \
    } while (0)

    float lA[4] = {}, lB[4] = {};
    f32x4 oA[4] = {}, oB[4] = {};

    const float SC = 0.125f * 1.44269504f;
    const int nktB = qtB + 1;

    int buf = 0;
    AST(0, 0);
    asm volatile("s_waitcnt vmcnt(0)" ::: "memory");
    __builtin_amdgcn_s_barrier();

    // One iteration: prefetch next K/V tile, then the interleaved 2-chain
    // compute, then drain + barrier + flip. DO_A/DIAG_A/DIAG_B are literals.
#define ITER(DO_A, DIAG_A, DIAG_B)                                              \
    do {                                                                        \
        const int kbase = kt * 64;                                              \
        if (kt + 1 < nktB) AST(buf ^ 1, kbase + 64);                            \
        f32x4 sB[4], sA[4];                                                     \
        QK_PART(sB, aqB, Ks2[buf]);                                             \
        if (DO_A) QK_PART(sA, aqA, Ks2[buf]);                                   \
        SM_PART(sB, lB, &Ps[0][w][0], DIAG_B, q0B);                             \
        if (DO_A) SM_PART(sA, lA, &Ps[1][w][0], DIAG_A, q0A);                   \
        PV_PART(oB, &Ps[0][w][0], Vts2[buf]);                                   \
        if (DO_A) PV_PART(oA, &Ps[1][w][0], Vts2[buf]);                         \
        asm volatile("s_waitcnt vmcnt(0)" ::: "memory");                        \
        __builtin_amdgcn_s_barrier();                                           \
        buf ^= 1;                                                               \
    } while (0)

    int kt = 0;
    // Phase 1: both tiles, no diag (kt < qtA).
#pragma unroll 1
    for (; kt < qtA; ++kt) ITER(true, false, false);
    // kt == qtA: both tiles, A hits its diagonal.
    ITER(true, true, false);
    ++kt;
    // Phase 3: B only, no diag (qtA < kt < qtB).
#pragma unroll 1
    for (; kt < qtB; ++kt) ITER(false, false, false);
    // kt == qtB: B diagonal.
    ITER(false, false, true);

#undef ITER
#undef AST

    ATTN_EPI(q0A, lA, oA);
    ATTN_EPI(q0B, lB, oB);
}

// ---------------------------------------------------------------------------
// Kernel 3: proj GEMM — R15 pipeline. 128x128 tile, 4 waves (2Mx2N), BK=32,
// 3-buffer LDS (48KB -> 3 blocks/CU), depth-2 prefetch, vmcnt(4)/tile. (R17)
// ---------------------------------------------------------------------------
__global__ __launch_bounds__(256, 3) void proj_mfma(
    const unsigned short* __restrict__ Y, const unsigned short* __restrict__ Wt,
    const float* __restrict__ bias, float* __restrict__ out)
{
    // XCD swizzle: 384 blocks, 384 % 8 == 0 -> bijective.
    const int wg = ((int)blockIdx.x & 7) * 48 + ((int)blockIdx.x >> 3);
    const int bx = wg % 6;
    const int by = wg / 6;
    const int n0 = bx * 128;
    const int m0 = by * 128;
    const int tid = threadIdx.x;
    const int lane = tid & 63;
    const int w = tid >> 6;        // 0..3
    const int wm = w >> 1;         // 0..1
    const int wn = w & 1;          // 0..1
    const int lm = lane & 15;
    const int lq = lane >> 4;

    __shared__ __align__(16) unsigned short lds[24576];  // 48 KiB (3 x 16KB)

    float bb[4];
#pragma unroll
    for (int ni = 0; ni < 4; ++ni) bb[ni] = bias[n0 + wn * 64 + ni * 16 + lm];

    f32x4 acc[4][4] = {};

    const int eo = lq ^ ((lm >> 1) & 3);
    int aoffc[4], boffc[4];
#pragma unroll
    for (int mi = 0; mi < 4; ++mi)
        aoffc[mi] = (wm * 64 + mi * 16 + lm) * 32 + eo * 8;
#pragma unroll
    for (int ni = 0; ni < 4; ++ni)
        boffc[ni] = 4096 + (wn * 64 + ni * 16 + lm) * 32 + eo * 8;

    size_t srcA[2];
    int srcB[2];
#pragma unroll
    for (int j = 0; j < 2; ++j) {
        const int lin = j * 256 + tid;
        const int row = lin >> 2;
        const int cc = (lin & 3) ^ ((row >> 1) & 3);
        const int m = m0 + row;
        srcA[j] = (size_t)(m >> 10) * 786432 + (size_t)(m & 1023) * 64 + cc * 8;
        srcB[j] = row * CDIM + cc * 8;       // + n0*CDIM + kt*32
    }
    const unsigned short* Wtb = Wt + (size_t)n0 * CDIM;

#define PSTAGE(p, kt)                                                           \
    do {                                                                        \
        const int hof = ((kt) >> 1) * 65536 + ((kt) & 1) * 32;                  \
        _Pragma("unroll")                                                       \
        for (int j = 0; j < 2; ++j)                                             \
            async_copy16(&lds[(p) * 8192 + (j * 256 + tid) * 8],                \
                         &Y[srcA[j] + hof]);                                    \
        _Pragma("unroll")                                                       \
        for (int j = 0; j < 2; ++j)                                             \
            async_copy16(&lds[(p) * 8192 + 4096 + (j * 256 + tid) * 8],         \
                         &Wtb[srcB[j] + (kt) * 32]);                            \
    } while (0)

#define PTILE(p, ktn)                                                           \
    do {                                                                        \
        PSTAGE((p + 2) % 3, ktn);                                               \
        bf16x8 a[4], b[4];                                                      \
        _Pragma("unroll")                                                       \
        for (int mi = 0; mi < 4; ++mi)                                          \
            a[mi] = *(const bf16x8*)&lds[(p) * 8192 + aoffc[mi]];               \
        _Pragma("unroll")                                                       \
        for (int ni = 0; ni < 4; ++ni)                                          \
            b[ni] = *(const bf16x8*)&lds[(p) * 8192 + boffc[ni]];               \
        __builtin_amdgcn_s_setprio(1);                                          \
        _Pragma("unroll")                                                       \
        for (int mi = 0; mi < 4; ++mi)                                          \
            _Pragma("unroll")                                                   \
            for (int ni = 0; ni < 4; ++ni)                                      \
                acc[mi][ni] = __builtin_amdgcn_mfma_f32_16x16x32_bf16(          \
                    a[mi], b[ni], acc[mi][ni], 0, 0, 0);                        \
        __builtin_amdgcn_s_setprio(0);                                          \
        asm volatile("s_waitcnt vmcnt(4)" ::: "memory");                        \
        __builtin_amdgcn_s_barrier();                                           \
    } while (0)

    PSTAGE(0, 0);
    PSTAGE(1, 1);
    asm volatile("s_waitcnt vmcnt(4)" ::: "memory");
    __builtin_amdgcn_s_barrier();

#pragma unroll 1
    for (int it = 0; it < 8; ++it) {
        const int k2 = (3 * it + 2 < 24) ? 3 * it + 2 : 23;
        const int k3 = (3 * it + 3 < 24) ? 3 * it + 3 : 23;  // clamp: dead
        const int k4 = (3 * it + 4 < 24) ? 3 * it + 4 : 23;  // restage benign
        PTILE(0, k2);
        PTILE(1, k3);
        PTILE(2, k4);
    }

#undef PSTAGE
#undef PTILE

    asm volatile("s_waitcnt vmcnt(0)" ::: "memory");

#pragma unroll
    for (int ni = 0; ni < 4; ++ni) {
        const int gn = n0 + wn * 64 + ni * 16 + lm;
#pragma unroll
        for (int mi = 0; mi < 4; ++mi) {
#pragma unroll
            for (int r = 0; r < 4; ++r) {
                const int gm = m0 + wm * 64 + mi * 16 + lq * 4 + r;
                out[(size_t)gm * CDIM + gn] = acc[mi][ni][r] + bb[ni];
            }
        }
    }
}

extern "C" void kernel_launch(void* const* d_in, const int* in_sizes, int n_in,
                              void* d_out, int out_size, void* d_ws, size_t ws_size,
                              hipStream_t stream) {
    const float* x      = (const float*)d_in[0];
    const float* W_attn = (const float*)d_in[1];
    const float* b_attn = (const float*)d_in[2];
    const float* W_proj = (const float*)d_in[3];
    const float* b_proj = (const float*)d_in[4];
    float* out = (float*)d_out;

    const size_t per = (size_t)8 * 12 * 1024 * 64;
    unsigned short* Q   = (unsigned short*)d_ws;
    unsigned short* K   = Q + per;
    unsigned short* Vt  = K + per;   // [B,H,D,T] transposed
    unsigned short* xb  = Vt + per;
    unsigned short* Wta = xb + (size_t)8192 * CDIM;
    unsigned short* Wtp = Wta + (size_t)NDIM * CDIM;

    precast<<<dim3(8448), 256, 0, stream>>>(x, xb, W_attn, Wta, W_proj, Wtp);

    qkv_mfma<<<dim3(576), 512, 0, stream>>>(xb, Wta, b_attn, Q, K, Vt);
    attn_mfma<<<dim3(8, 96), 256, 0, stream>>>(Q, K, Vt, Q);
    proj_mfma<<<dim3(384), 256, 0, stream>>>(Q, Wtp, b_proj, out);
}

// Round 10
// 180.686 us; speedup vs baseline: 1.0491x; 1.0491x over previous
//
#include <hip/hip_runtime.h>
#include <hip/hip_bf16.h>

// Problem: B=8, T=1024, C=768, H=12, HD=64. M = 8192. fp32 in/out.
// R23: REVERT attn to the R16 serial structure (R22's 2-chain interleave
// regressed 67us vs <45: +32 live regs (VGPR 92) forced the scheduler to
// serialize the chains; same-wave MFMAs serialize on the matrix pipe anyway,
// and cross-WAVE TLP was already the latency cover). Kept from R22 only the
// compile-time diag peel: phase loops with DIAG as a literal, so non-diag
// tiles (15 of ~17) carry no mask cmp/cndmask. Single Ps buffer, R16 staging,
// identical per-value arithmetic order -> bit-identical output.
// qkv (R15) + proj (R17) + precast (R17) unchanged.

#define TDIM 1024
#define CDIM 768
#define NDIM 2304

typedef __attribute__((ext_vector_type(8))) short bf16x8;
typedef __attribute__((ext_vector_type(8))) unsigned short u16x8;
typedef __attribute__((ext_vector_type(4))) float f32x4;

__device__ __forceinline__ unsigned short f2bf(float f) {
    unsigned int u;
    __builtin_memcpy(&u, &f, 4);
    u += 0x7FFFu + ((u >> 16) & 1u);  // RNE
    return (unsigned short)(u >> 16);
}

__device__ __forceinline__ void async_copy16(void* lds, const void* g) {
    __builtin_amdgcn_global_load_lds(
        (const __attribute__((address_space(1))) void*)g,
        (__attribute__((address_space(3))) void*)lds, 16, 0, 0);
}

// ---------------------------------------------------------------------------
// Precast: one fat kernel. Blocks [0,6144): cast x -> xb (bf16).
// [6144,7872): transpose-cast W_attn -> Wta. [7872,8448): W_proj -> Wtp.
// ---------------------------------------------------------------------------
__global__ __launch_bounds__(256) void precast(
    const float* __restrict__ x, unsigned short* __restrict__ xb,
    const float* __restrict__ Wa, unsigned short* __restrict__ Wta,
    const float* __restrict__ Wp, unsigned short* __restrict__ Wtp)
{
    __shared__ float tile[32][33];
    int bid = blockIdx.x;
    const int tid = threadIdx.x;

    if (bid < 6144) {
        const size_t i = ((size_t)bid * 256 + tid) * 4;
        float4 v = *(const float4*)&x[i];
        ushort4 s;
        s.x = f2bf(v.x); s.y = f2bf(v.y); s.z = f2bf(v.z); s.w = f2bf(v.w);
        *(ushort4*)&xb[i] = s;
        return;
    }
    bid -= 6144;
    const float* W;
    unsigned short* Wt;
    int N, bx, by;
    if (bid < 1728) {
        W = Wa; Wt = Wta; N = NDIM; bx = bid % 72; by = bid / 72;
    } else {
        bid -= 1728;
        W = Wp; Wt = Wtp; N = CDIM; bx = bid % 24; by = bid / 24;
    }
    const int n0 = bx * 32;
    const int k0 = by * 32;
    const int tx = tid & 31;
    const int ty = tid >> 5;
#pragma unroll
    for (int i = 0; i < 4; ++i)
        tile[ty + i * 8][tx] = W[(size_t)(k0 + ty + i * 8) * N + n0 + tx];
    __syncthreads();
#pragma unroll
    for (int i = 0; i < 4; ++i)
        Wt[(size_t)(n0 + ty + i * 8) * CDIM + k0 + tx] = f2bf(tile[tx][ty + i * 8]);
}

// ---------------------------------------------------------------------------
// Kernel 1: qkv GEMM — 128(M) x 256(N) tile, BK=32, 8 waves (2M x 4N),
// 3-buffer LDS, depth-2 prefetch, vmcnt(3) per tile, 2 blocks/CU. (R15)
// ---------------------------------------------------------------------------
__global__ __launch_bounds__(512, 4) void qkv_mfma(
    const unsigned short* __restrict__ xb, const unsigned short* __restrict__ Wt,
    const float* __restrict__ bias,
    unsigned short* __restrict__ Q, unsigned short* __restrict__ Kd,
    unsigned short* __restrict__ Vt)
{
    // XCD-aware swizzle: 576 blocks, 576 % 8 == 0 -> bijective.
    const int wg = ((int)blockIdx.x & 7) * 72 + ((int)blockIdx.x >> 3);
    const int bx = wg % 9;
    const int by = wg / 9;
    const int n0 = bx * 256;
    const int m0 = by * 128;
    const int tid = threadIdx.x;
    const int lane = tid & 63;
    const int w = tid >> 6;
    const int wm = w >> 2;   // 0..1
    const int wn = w & 3;    // 0..3
    const int lm = lane & 15;
    const int lq = lane >> 4;

    __shared__ __align__(16) unsigned short lds[36864];  // 72 KiB (3 x 24KB)

    float bb[4];
#pragma unroll
    for (int ni = 0; ni < 4; ++ni) bb[ni] = bias[n0 + wn * 64 + ni * 16 + lm];

    f32x4 acc[4][4] = {};

    // ds_read swizzled chunk: eo = lq ^ ((lm>>1)&3).
    const int eo = lq ^ ((lm >> 1) & 3);
    int aoffc[4], boffc[4];
#pragma unroll
    for (int mi = 0; mi < 4; ++mi)
        aoffc[mi] = (wm * 64 + mi * 16 + lm) * 32 + eo * 8;
#pragma unroll
    for (int ni = 0; ni < 4; ++ni)
        boffc[ni] = 4096 + (wn * 64 + ni * 16 + lm) * 32 + eo * 8;

    const int rowA = tid >> 2;
    const int ccA = (tid & 3) ^ ((rowA >> 1) & 3);
    const int srcA = rowA * CDIM + ccA * 8;          // + m0*CDIM + kt*32
    int srcB[2];
#pragma unroll
    for (int j = 0; j < 2; ++j) {
        const int lin = j * 512 + tid;
        const int rowB = lin >> 2;
        const int ccB = (lin & 3) ^ ((rowB >> 1) & 3);
        srcB[j] = rowB * CDIM + ccB * 8;             // + n0*CDIM + kt*32
    }
    const unsigned short* xbb = xb + (size_t)m0 * CDIM;
    const unsigned short* Wtb = Wt + (size_t)n0 * CDIM;

#define STAGE(p, kt)                                                            \
    do {                                                                        \
        async_copy16(&lds[(p) * 12288 + w * 512], &xbb[srcA + (kt) * 32]);      \
        _Pragma("unroll")                                                       \
        for (int j = 0; j < 2; ++j)                                             \
            async_copy16(&lds[(p) * 12288 + 4096 + j * 4096 + w * 512],         \
                         &Wtb[srcB[j] + (kt) * 32]);                            \
    } while (0)

#define TILE(p, ktn)                                                            \
    do {                                                                        \
        STAGE((p + 2) % 3, ktn);                                                \
        bf16x8 a[4], b[4];                                                      \
        _Pragma("unroll")                                                       \
        for (int mi = 0; mi < 4; ++mi)                                          \
            a[mi] = *(const bf16x8*)&lds[(p) * 12288 + aoffc[mi]];              \
        _Pragma("unroll")                                                       \
        for (int ni = 0; ni < 4; ++ni)                                          \
            b[ni] = *(const bf16x8*)&lds[(p) * 12288 + boffc[ni]];              \
        __builtin_amdgcn_s_setprio(1);                                          \
        _Pragma("unroll")                                                       \
        for (int mi = 0; mi < 4; ++mi)                                          \
            _Pragma("unroll")                                                   \
            for (int ni = 0; ni < 4; ++ni)                                      \
                acc[mi][ni] = __builtin_amdgcn_mfma_f32_16x16x32_bf16(          \
                    a[mi], b[ni], acc[mi][ni], 0, 0, 0);                        \
        __builtin_amdgcn_s_setprio(0);                                          \
        asm volatile("s_waitcnt vmcnt(3)" ::: "memory");                        \
        __builtin_amdgcn_s_barrier();                                           \
    } while (0)

    STAGE(0, 0);
    STAGE(1, 1);
    asm volatile("s_waitcnt vmcnt(3)" ::: "memory");
    __builtin_amdgcn_s_barrier();

#pragma unroll 1
    for (int it = 0; it < 8; ++it) {
        const int k2 = (3 * it + 2 < 24) ? 3 * it + 2 : 23;
        const int k3 = (3 * it + 3 < 24) ? 3 * it + 3 : 23;  // clamp: dead
        const int k4 = (3 * it + 4 < 24) ? 3 * it + 4 : 23;  // restage benign
        TILE(0, k2);
        TILE(1, k3);
        TILE(2, k4);
    }

#undef STAGE
#undef TILE

    // Drain all outstanding DMA before reusing LDS as epilogue scratch.
    asm volatile("s_waitcnt vmcnt(0)" ::: "memory");
    __builtin_amdgcn_s_barrier();

    // Epilogue. Wave's 64-col group: ga = bx*4 + wn; which = ga%3; h = ga/3.
    const int ga = bx * 4 + wn;
    const int which = ga % 3;
    const int h = ga / 3;

    if (which == 2) {
        // V transposed [B,H,D,T]: direct t-contiguous ushort4 stores.
#pragma unroll
        for (int ni = 0; ni < 4; ++ni) {
            const int d = ni * 16 + lm;
#pragma unroll
            for (int mi = 0; mi < 4; ++mi) {
                const int gm0 = m0 + wm * 64 + mi * 16 + lq * 4;
                const int bidx = gm0 >> 10;
                const int t0 = gm0 & 1023;
                ushort4 sv;
                sv.x = f2bf(acc[mi][ni][0] + bb[ni]);
                sv.y = f2bf(acc[mi][ni][1] + bb[ni]);
                sv.z = f2bf(acc[mi][ni][2] + bb[ni]);
                sv.w = f2bf(acc[mi][ni][3] + bb[ni]);
                *(ushort4*)&Vt[(((size_t)bidx * 12 + h) * 64 + d) * TDIM + t0] = sv;
            }
        }
    } else {
        // Q/K [B,H,T,64]: per-wave LDS transpose -> 16B row stores.
        unsigned short* dst = (which == 0) ? Q : Kd;
        unsigned short* Es = &lds[w * 1152];  // 16 x 72 per wave
        const int erow = lane >> 2;   // 0..15
        const int ecol = lane & 3;    // 0..3 -> 16-short chunks
#pragma unroll
        for (int mi = 0; mi < 4; ++mi) {
#pragma unroll
            for (int r = 0; r < 4; ++r)
#pragma unroll
                for (int ni = 0; ni < 4; ++ni)
                    Es[(lq * 4 + r) * 72 + ni * 16 + lm] = f2bf(acc[mi][ni][r] + bb[ni]);
            // same-wave LDS write->read (in-order per wave; validated since R7)
            const int t = m0 + wm * 64 + mi * 16 + erow;
            const int bidx = t >> 10;
            const int tt = t & 1023;
            unsigned short* drow = &dst[(((size_t)bidx * 12 + h) * TDIM + tt) * 64];
            u16x8 v0 = *(const u16x8*)&Es[erow * 72 + ecol * 16];
            u16x8 v1 = *(const u16x8*)&Es[erow * 72 + ecol * 16 + 8];
            *(u16x8*)&drow[ecol * 16] = v0;
            *(u16x8*)&drow[ecol * 16 + 8] = v1;
        }
    }
}

// ---------------------------------------------------------------------------
// Kernel 2: MFMA causal flash attention v7 — serial R16 tile structure
// (full QK->SM->PV per tile, single Ps buffer), compile-time diag peel.
// Bit-identical arithmetic to v5/v6.
// ---------------------------------------------------------------------------
#define ATTN_TILE(aq, q0t, l_p, o, DIAG) do {                                   \
    float pf[4][4];                                                             \
    _Pragma("unroll")                                                           \
    for (int nt = 0; nt < 4; ++nt) {                                            \
        f32x4 s = {};                                                           \
        _Pragma("unroll")                                                       \
        for (int kc = 0; kc < 2; ++kc) {                                        \
            bf16x8 bfrag = *(const bf16x8*)&Ks2[buf][(nt * 16 + lm) * 64 + cofs[kc]]; \
            s = __builtin_amdgcn_mfma_f32_16x16x32_bf16(aq[kc], bfrag, s, 0, 0, 0); \
        }                                                                       \
        _Pragma("unroll")                                                       \
        for (int r = 0; r < 4; ++r) {                                           \
            float p = __builtin_amdgcn_exp2f(s[r] * SC);                        \
            if (DIAG) {                                                         \
                const int keyg = kbase + nt * 16 + lm;                          \
                const int qg = (q0t) + w * 16 + lq * 4 + r;                     \
                if (keyg > qg) p = 0.f;                                         \
            }                                                                   \
            pf[nt][r] = p;                                                      \
        }                                                                       \
    }                                                                           \
    _Pragma("unroll")                                                           \
    for (int r = 0; r < 4; ++r) {                                               \
        l_p[r] += pf[0][r] + pf[1][r] + pf[2][r] + pf[3][r];                    \
        _Pragma("unroll")                                                       \
        for (int nt = 0; nt < 4; ++nt)                                          \
            Ps[w][lq * 4 + r][nt * 16 + lm] = f2bf(pf[nt][r]);                  \
    }                                                                           \
    {                                                                           \
        bf16x8 ap[2];                                                           \
        _Pragma("unroll")                                                       \
        for (int kc = 0; kc < 2; ++kc)                                          \
            ap[kc] = *(const bf16x8*)&Ps[w][lm][kc * 32 + lq * 8];              \
        _Pragma("unroll")                                                       \
        for (int nt = 0; nt < 4; ++nt) {                                        \
            _Pragma("unroll")                                                   \
            for (int kc = 0; kc < 2; ++kc) {                                    \
                bf16x8 bv = *(const bf16x8*)&Vts2[buf][(nt * 16 + lm) * 64 + cofs[kc]]; \
                o[nt] = __builtin_amdgcn_mfma_f32_16x16x32_bf16(ap[kc], bv, o[nt], 0, 0, 0); \
            }                                                                   \
        }                                                                       \
    }                                                                           \
} while (0)

#define ATTN_EPI(q0t, l_p, o) do {                                              \
    _Pragma("unroll")                                                           \
    for (int r = 0; r < 4; ++r) {                                               \
        float l = l_p[r];                                                       \
        _Pragma("unroll")                                                       \
        for (int off = 1; off < 16; off <<= 1) l += __shfl_xor(l, off);         \
        const float inv = 1.0f / l;                                             \
        const int qg = (q0t) + w * 16 + lq * 4 + r;                             \
        _Pragma("unroll")                                                       \
        for (int nt = 0; nt < 4; ++nt)                                          \
            Yb[(size_t)qg * 64 + nt * 16 + lm] = f2bf(o[nt][r] * inv);          \
    }                                                                           \
} while (0)

__global__ __launch_bounds__(256) void attn_mfma(
    const unsigned short* __restrict__ Q, const unsigned short* __restrict__ K,
    const unsigned short* __restrict__ Vt, unsigned short* __restrict__ Y)
{
    const int pi = blockIdx.x;        // 0..7 -> 64-query tiles (pi, 15-pi)
    const int bh = blockIdx.y;        // 0..95
    const int qtA = pi, qtB = 15 - pi;
    const int q0A = qtA * 64, q0B = qtB * 64;
    const int tid = threadIdx.x;
    const int lane = tid & 63;
    const int w = tid >> 6;
    const int lm = lane & 15;
    const int lq = lane >> 4;

    __shared__ __align__(16) unsigned short Ks2[2][4096];   // [buf][64*64] linear
    __shared__ __align__(16) unsigned short Vts2[2][4096];  // [buf][d*64+key]
    __shared__ __align__(16) unsigned short Ps[4][16][72];

    const unsigned short* Qb = Q + (size_t)bh * TDIM * 64;
    const unsigned short* Kb = K + (size_t)bh * TDIM * 64;
    const unsigned short* Vtb = Vt + (size_t)bh * 64 * TDIM;
    unsigned short* Yb = Y + (size_t)bh * TDIM * 64;

    bf16x8 aqA[2], aqB[2];
#pragma unroll
    for (int kc = 0; kc < 2; ++kc) {
        aqA[kc] = *(const bf16x8*)&Qb[(size_t)(q0A + w * 16 + lm) * 64 + kc * 32 + lq * 8];
        aqB[kc] = *(const bf16x8*)&Qb[(size_t)(q0B + w * 16 + lm) * 64 + kc * 32 + lq * 8];
    }

    int dstO[2], srcK[2], srcV[2];
#pragma unroll
    for (int it = 0; it < 2; ++it) {
        const int idx = it * 256 + tid;
        const int row = idx >> 3;
        const int cc = (idx & 7) ^ (row & 7);
        dstO[it] = idx * 8;                 // shorts
        srcK[it] = row * 64 + cc * 8;       // + kbase*64
        srcV[it] = row * TDIM + cc * 8;     // + kbase
    }
    int cofs[2];
#pragma unroll
    for (int kc = 0; kc < 2; ++kc)
        cofs[kc] = (((kc * 4 + lq) ^ (lm & 7)) * 8);

#define AST(bf, kb)                                                             \
    do {                                                                        \
        _Pragma("unroll")                                                       \
        for (int it = 0; it < 2; ++it) {                                        \
            async_copy16(&Ks2[bf][dstO[it]], &Kb[(size_t)(kb) * 64 + srcK[it]]); \
            async_copy16(&Vts2[bf][dstO[it]], &Vtb[(size_t)(kb) + srcV[it]]);   \
        }                                                                       \
    } while (0)

#define ENDIT()                                                                 \
    do {                                                                        \
        asm volatile("s_waitcnt vmcnt(0)" ::: "memory");                        \
        __builtin_amdgcn_s_barrier();                                           \
        buf ^= 1;                                                               \
    } while (0)

    float lA[4] = {}, lB[4] = {};
    f32x4 oA[4] = {}, oB[4] = {};

    const float SC = 0.125f * 1.44269504f;

    int buf = 0;
    AST(0, 0);
    asm volatile("s_waitcnt vmcnt(0)" ::: "memory");
    __builtin_amdgcn_s_barrier();

    int kt = 0;
    // Phase 1: both tiles, no diag (kt < qtA).
#pragma unroll 1
    for (; kt < qtA; ++kt) {
        const int kbase = kt * 64;
        AST(buf ^ 1, kbase + 64);
        ATTN_TILE(aqB, q0B, lB, oB, 0);
        ATTN_TILE(aqA, q0A, lA, oA, 0);
        ENDIT();
    }
    // kt == qtA: A hits its diagonal (qtA < qtB always -> prefetch valid).
    {
        const int kbase = kt * 64;
        AST(buf ^ 1, kbase + 64);
        ATTN_TILE(aqB, q0B, lB, oB, 0);
        ATTN_TILE(aqA, q0A, lA, oA, 1);
        ENDIT();
        ++kt;
    }
    // Phase 3: B only, no diag (qtA < kt < qtB).
#pragma unroll 1
    for (; kt < qtB; ++kt) {
        const int kbase = kt * 64;
        AST(buf ^ 1, kbase + 64);
        ATTN_TILE(aqB, q0B, lB, oB, 0);
        ENDIT();
    }
    // kt == qtB: B diagonal, no prefetch.
    {
        const int kbase = kt * 64;
        ATTN_TILE(aqB, q0B, lB, oB, 1);
    }

#undef ENDIT
#undef AST

    ATTN_EPI(q0A, lA, oA);
    ATTN_EPI(q0B, lB, oB);
}

// ---------------------------------------------------------------------------
// Kernel 3: proj GEMM — R15 pipeline. 128x128 tile, 4 waves (2Mx2N), BK=32,
// 3-buffer LDS (48KB -> 3 blocks/CU), depth-2 prefetch, vmcnt(4)/tile. (R17)
// ---------------------------------------------------------------------------
__global__ __launch_bounds__(256, 3) void proj_mfma(
    const unsigned short* __restrict__ Y, const unsigned short* __restrict__ Wt,
    const float* __restrict__ bias, float* __restrict__ out)
{
    // XCD swizzle: 384 blocks, 384 % 8 == 0 -> bijective.
    const int wg = ((int)blockIdx.x & 7) * 48 + ((int)blockIdx.x >> 3);
    const int bx = wg % 6;
    const int by = wg / 6;
    const int n0 = bx * 128;
    const int m0 = by * 128;
    const int tid = threadIdx.x;
    const int lane = tid & 63;
    const int w = tid >> 6;        // 0..3
    const int wm = w >> 1;         // 0..1
    const int wn = w & 1;          // 0..1
    const int lm = lane & 15;
    const int lq = lane >> 4;

    __shared__ __align__(16) unsigned short lds[24576];  // 48 KiB (3 x 16KB)

    float bb[4];
#pragma unroll
    for (int ni = 0; ni < 4; ++ni) bb[ni] = bias[n0 + wn * 64 + ni * 16 + lm];

    f32x4 acc[4][4] = {};

    const int eo = lq ^ ((lm >> 1) & 3);
    int aoffc[4], boffc[4];
#pragma unroll
    for (int mi = 0; mi < 4; ++mi)
        aoffc[mi] = (wm * 64 + mi * 16 + lm) * 32 + eo * 8;
#pragma unroll
    for (int ni = 0; ni < 4; ++ni)
        boffc[ni] = 4096 + (wn * 64 + ni * 16 + lm) * 32 + eo * 8;

    size_t srcA[2];
    int srcB[2];
#pragma unroll
    for (int j = 0; j < 2; ++j) {
        const int lin = j * 256 + tid;
        const int row = lin >> 2;
        const int cc = (lin & 3) ^ ((row >> 1) & 3);
        const int m = m0 + row;
        srcA[j] = (size_t)(m >> 10) * 786432 + (size_t)(m & 1023) * 64 + cc * 8;
        srcB[j] = row * CDIM + cc * 8;       // + n0*CDIM + kt*32
    }
    const unsigned short* Wtb = Wt + (size_t)n0 * CDIM;

#define PSTAGE(p, kt)                                                           \
    do {                                                                        \
        const int hof = ((kt) >> 1) * 65536 + ((kt) & 1) * 32;                  \
        _Pragma("unroll")                                                       \
        for (int j = 0; j < 2; ++j)                                             \
            async_copy16(&lds[(p) * 8192 + (j * 256 + tid) * 8],                \
                         &Y[srcA[j] + hof]);                                    \
        _Pragma("unroll")                                                       \
        for (int j = 0; j < 2; ++j)                                             \
            async_copy16(&lds[(p) * 8192 + 4096 + (j * 256 + tid) * 8],         \
                         &Wtb[srcB[j] + (kt) * 32]);                            \
    } while (0)

#define PTILE(p, ktn)                                                           \
    do {                                                                        \
        PSTAGE((p + 2) % 3, ktn);                                               \
        bf16x8 a[4], b[4];                                                      \
        _Pragma("unroll")                                                       \
        for (int mi = 0; mi < 4; ++mi)                                          \
            a[mi] = *(const bf16x8*)&lds[(p) * 8192 + aoffc[mi]];               \
        _Pragma("unroll")                                                       \
        for (int ni = 0; ni < 4; ++ni)                                          \
            b[ni] = *(const bf16x8*)&lds[(p) * 8192 + boffc[ni]];               \
        __builtin_amdgcn_s_setprio(1);                                          \
        _Pragma("unroll")                                                       \
        for (int mi = 0; mi < 4; ++mi)                                          \
            _Pragma("unroll")                                                   \
            for (int ni = 0; ni < 4; ++ni)                                      \
                acc[mi][ni] = __builtin_amdgcn_mfma_f32_16x16x32_bf16(          \
                    a[mi], b[ni], acc[mi][ni], 0, 0, 0);                        \
        __builtin_amdgcn_s_setprio(0);                                          \
        asm volatile("s_waitcnt vmcnt(4)" ::: "memory");                        \
        __builtin_amdgcn_s_barrier();                                           \
    } while (0)

    PSTAGE(0, 0);
    PSTAGE(1, 1);
    asm volatile("s_waitcnt vmcnt(4)" ::: "memory");
    __builtin_amdgcn_s_barrier();

#pragma unroll 1
    for (int it = 0; it < 8; ++it) {
        const int k2 = (3 * it + 2 < 24) ? 3 * it + 2 : 23;
        const int k3 = (3 * it + 3 < 24) ? 3 * it + 3 : 23;  // clamp: dead
        const int k4 = (3 * it + 4 < 24) ? 3 * it + 4 : 23;  // restage benign
        PTILE(0, k2);
        PTILE(1, k3);
        PTILE(2, k4);
    }

#undef PSTAGE
#undef PTILE

    asm volatile("s_waitcnt vmcnt(0)" ::: "memory");

#pragma unroll
    for (int ni = 0; ni < 4; ++ni) {
        const int gn = n0 + wn * 64 + ni * 16 + lm;
#pragma unroll
        for (int mi = 0; mi < 4; ++mi) {
#pragma unroll
            for (int r = 0; r < 4; ++r) {
                const int gm = m0 + wm * 64 + mi * 16 + lq * 4 + r;
                out[(size_t)gm * CDIM + gn] = acc[mi][ni][r] + bb[ni];
            }
        }
    }
}

extern "C" void kernel_launch(void* const* d_in, const int* in_sizes, int n_in,
                              void* d_out, int out_size, void* d_ws, size_t ws_size,
                              hipStream_t stream) {
    const float* x      = (const float*)d_in[0];
    const float* W_attn = (const float*)d_in[1];
    const float* b_attn = (const float*)d_in[2];
    const float* W_proj = (const float*)d_in[3];
    const float* b_proj = (const float*)d_in[4];
    float* out = (float*)d_out;

    const size_t per = (size_t)8 * 12 * 1024 * 64;
    unsigned short* Q   = (unsigned short*)d_ws;
    unsigned short* K   = Q + per;
    unsigned short* Vt  = K + per;   // [B,H,D,T] transposed
    unsigned short* xb  = Vt + per;
    unsigned short* Wta = xb + (size_t)8192 * CDIM;
    unsigned short* Wtp = Wta + (size_t)NDIM * CDIM;

    precast<<<dim3(8448), 256, 0, stream>>>(x, xb, W_attn, Wta, W_proj, Wtp);

    qkv_mfma<<<dim3(576), 512, 0, stream>>>(xb, Wta, b_attn, Q, K, Vt);
    attn_mfma<<<dim3(8, 96), 256, 0, stream>>>(Q, K, Vt, Q);
    proj_mfma<<<dim3(384), 256, 0, stream>>>(Q, Wtp, b_proj, out);
}